// Round 7
// baseline (388.609 us; speedup 1.0000x reference)
//
#include <hip/hip_runtime.h>
#include <cstdint>
#include <cstddef>

// Problem constants (fixed by the reference: B=8192, F=1024, N=4096)
#define B_DIM 8192
#define F_DIM 1024
#define N_DIM 4096

// GEMM tiling: 128x128 block tile, 4 waves (2x2), 64x64 per wave, BK=128 fp8.
// R4 (256x128): reg-cliff 2x regression. R6 (force 128 regs): spills to
// scratch (WRITE_SIZE 16->61 MB), regression. True need ~140 regs -> 3
// waves/SIMD by regs. R5 was latency-bound: LDS 43% / MFMA 23% busy, stall =
// per-iter vmcnt(0) drain of just-issued global_load_lds.
// R7: double-buffered LDS (64 KB, the WG limit), staging issued one full
// iteration ahead -> the barrier drain waits on ~2000-cy-old loads (~free).
#define BM 128
#define BN 128
#define BK 128

typedef float floatx4 __attribute__((ext_vector_type(4)));
typedef int intx4 __attribute__((ext_vector_type(4)));
typedef int intx8 __attribute__((ext_vector_type(8)));

typedef const __attribute__((address_space(1))) unsigned int* as1_u32cp;
typedef __attribute__((address_space(3))) unsigned int* as3_u32p;

// Async global->LDS 16B copy. LDS dest is wave-uniform base + lane*16.
__device__ __forceinline__ void gload_lds16(const uint8_t* g, uint8_t* l) {
    __builtin_amdgcn_global_load_lds((as1_u32cp)(const unsigned int*)g,
                                     (as3_u32p)(unsigned int*)l, 16, 0, 0);
}

__device__ __forceinline__ float hardswish_f(float l) {
    float g = fminf(fmaxf(l + 3.0f, 0.0f), 6.0f);
    return l * g * (1.0f / 6.0f);
}

// Merged fp32 -> fp8 e4m3 conversion for x|y|w (dst contiguous in ws), plus a
// grid tail that zeroes rowsum (replaces a separate hipMemsetAsync dispatch).
__global__ __launch_bounds__(256) void cvt_all_kernel(
    const float* __restrict__ x, const float* __restrict__ y,
    const float* __restrict__ wt, uint8_t* __restrict__ dst,
    float* __restrict__ rowsum, int n16x, int n16w) {
    int i = blockIdx.x * 256 + threadIdx.x;
    int total = 2 * n16x + n16w;
    if (i >= total) {
        int r = i - total;
        if (r < B_DIM / 4) ((float4*)rowsum)[r] = make_float4(0.f, 0.f, 0.f, 0.f);
        return;
    }
    const float* src;
    int j;
    if (i < n16x) { src = x; j = i; }
    else if (i < 2 * n16x) { src = y; j = i - n16x; }
    else { src = wt; j = i - 2 * n16x; }
    const float4* s4 = (const float4*)src + 4 * (size_t)j;
    intx4 o;
#pragma unroll
    for (int q = 0; q < 4; ++q) {
        float4 v = s4[q];
        int p = __builtin_amdgcn_cvt_pk_fp8_f32(v.x, v.y, 0, false);
        p = __builtin_amdgcn_cvt_pk_fp8_f32(v.z, v.w, p, true);
        o[q] = p;
    }
    *(intx4*)(dst + 16 * (size_t)i) = o;
}

// C = A * B^T, A[M][K], Bm[N][K] row-major fp8 e4m3, fp32 accumulate via
// mfma_scale_f32_16x16x128_f8f6f4 with unit scales (E8M0 0x7F = 2^0).
// LDS XOR-swizzled in 16B chunks: slot (row,c) holds global chunk c^(row&7).
// A-fragment (16x16x128): row=lane&15, k = quad*32 + reg*4 + byte
// -> 32 contiguous bytes = swizzled chunks {(2q)^e, (2q+1)^e}, e=row&7.
// C/D layout: col=lane&15, row=quad*4+reg.
// K-loop: double-buffered LDS (2x(16+16) KB = 64 KB, the WG limit; 2 blocks/CU),
// single __syncthreads per iter, staging for kt+1 issued right after the
// barrier so the next barrier's implicit vmcnt(0) drain is ~free.
// MODE 1: epilogue sums exp(C[i][j]) into rowsum[i] (scores never hit HBM).
// MODE 2: epilogue out = clamp(C + bias + hardswish(log(rowsum[row])), -1, 1)
//         (recomputed per-lane from L2 -- no LDS left for a broadcast array).
template <int MODE>
__global__ __launch_bounds__(256, 2) void gemm_bt_kernel(
    const uint8_t* __restrict__ A,
    const uint8_t* __restrict__ Bm,
    int M, int N, int K,
    float* __restrict__ rowsum,
    const float* __restrict__ bias,
    float* __restrict__ out) {
    __shared__ __align__(16) uint8_t As[2][BM * BK];   // 2 x 16 KB
    __shared__ __align__(16) uint8_t Bs[2][BN * BK];   // 2 x 16 KB  (total 64 KB)

    const int t = threadIdx.x;
    const int w = t >> 6;
    const int lane = t & 63;
    const int quad = lane >> 4;
    const int lc = lane & 15;
    const int wm = w >> 1;   // wave row (0..1), 64 rows each
    const int wn = w & 1;    // wave col (0..1), 64 cols each
    const int rowBase = blockIdx.y * BM;
    const int colBase = blockIdx.x * BN;

    floatx4 acc[4][4];
#pragma unroll
    for (int mi = 0; mi < 4; ++mi)
#pragma unroll
        for (int ni = 0; ni < 4; ++ni)
            acc[mi][ni] = (floatx4){0.f, 0.f, 0.f, 0.f};

    // Per-thread staging indices (idx = c*256 + t)
    const int nIter = K / BK;

    // Prologue: stage tile 0 into buffer 0
#pragma unroll
    for (int c = 0; c < 4; ++c) {
        const int idx = c * 256 + t;
        const int row = idx >> 3;
        const int cg = (idx & 7) ^ (row & 7);
        gload_lds16(A + (size_t)(rowBase + row) * K + cg * 16, As[0] + idx * 16);
        gload_lds16(Bm + (size_t)(colBase + row) * K + cg * 16, Bs[0] + idx * 16);
    }

    for (int kt = 0; kt < nIter; ++kt) {
        const int cur = kt & 1;
        __syncthreads();  // drains tile-kt staging (issued one iter ago: ~free)
        if (kt + 1 < nIter) {
            const int nxt = cur ^ 1;
#pragma unroll
            for (int c = 0; c < 4; ++c) {
                const int idx = c * 256 + t;
                const int row = idx >> 3;
                const int cg = (idx & 7) ^ (row & 7);
                gload_lds16(A + (size_t)(rowBase + row) * K + (kt + 1) * BK + cg * 16,
                            As[nxt] + idx * 16);
                gload_lds16(Bm + (size_t)(colBase + row) * K + (kt + 1) * BK + cg * 16,
                            Bs[nxt] + idx * 16);
            }
        }

        const uint8_t* Ac = As[cur];
        const uint8_t* Bc = Bs[cur];
        intx8 af[4], bf[4];
#pragma unroll
        for (int mi = 0; mi < 4; ++mi) {
            const int row = wm * 64 + mi * 16 + lc;
            const int e = row & 7;
            ((intx4*)&af[mi])[0] = *(const intx4*)(Ac + row * BK + ((2 * quad) ^ e) * 16);
            ((intx4*)&af[mi])[1] = *(const intx4*)(Ac + row * BK + ((2 * quad + 1) ^ e) * 16);
        }
#pragma unroll
        for (int ni = 0; ni < 4; ++ni) {
            const int row = wn * 64 + ni * 16 + lc;
            const int e = row & 7;
            ((intx4*)&bf[ni])[0] = *(const intx4*)(Bc + row * BK + ((2 * quad) ^ e) * 16);
            ((intx4*)&bf[ni])[1] = *(const intx4*)(Bc + row * BK + ((2 * quad + 1) ^ e) * 16);
        }
#pragma unroll
        for (int mi = 0; mi < 4; ++mi)
#pragma unroll
            for (int ni = 0; ni < 4; ++ni)
                acc[mi][ni] = __builtin_amdgcn_mfma_scale_f32_16x16x128_f8f6f4(
                    af[mi], bf[ni], acc[mi][ni],
                    0, 0,                      // cbsz=fp8(e4m3), blgp=fp8(e4m3)
                    0, 0x7F7F7F7F,             // A scale: 1.0
                    0, 0x7F7F7F7F);            // B scale: 1.0
    }

    if constexpr (MODE == 1) {
        // sum exp over this wave's 64 columns for each of its 64 rows
#pragma unroll
        for (int mi = 0; mi < 4; ++mi) {
#pragma unroll
            for (int r = 0; r < 4; ++r) {
                float p = 0.f;
#pragma unroll
                for (int ni = 0; ni < 4; ++ni) p += __expf(acc[mi][ni][r]);
                // butterfly over the 16 columns held by this quad's 16 lanes
                p += __shfl_xor(p, 1, 16);
                p += __shfl_xor(p, 2, 16);
                p += __shfl_xor(p, 4, 16);
                p += __shfl_xor(p, 8, 16);
                if (lc == 0) {
                    int row = rowBase + wm * 64 + mi * 16 + quad * 4 + r;
                    atomicAdd(&rowsum[row], p);
                }
            }
        }
    } else {
#pragma unroll
        for (int mi = 0; mi < 4; ++mi) {
            const int lrow = wm * 64 + mi * 16 + quad * 4;
            float av[4];
#pragma unroll
            for (int r = 0; r < 4; ++r)
                av[r] = hardswish_f(logf(rowsum[rowBase + lrow + r]));
#pragma unroll
            for (int ni = 0; ni < 4; ++ni) {
                const int col = colBase + wn * 64 + ni * 16 + lc;
                const float bv = bias[col];
#pragma unroll
                for (int r = 0; r < 4; ++r) {
                    float v = acc[mi][ni][r] + bv + av[r];
                    v = fminf(fmaxf(v, -1.0f), 1.0f);
                    out[(size_t)(rowBase + lrow + r) * N + col] = v;
                }
            }
        }
    }
}

extern "C" void kernel_launch(void* const* d_in, const int* in_sizes, int n_in,
                              void* d_out, int out_size, void* d_ws, size_t ws_size,
                              hipStream_t stream) {
    const float* x = (const float*)d_in[0];     // [B, F]
    const float* y = (const float*)d_in[1];     // [B, F]
    const float* wt = (const float*)d_in[2];    // [N, F]
    const float* bias = (const float*)d_in[3];  // [N]
    float* out = (float*)d_out;                 // [B, N]

    // Workspace: xq 8MB | yq 8MB | wq 4MB | rowsum 32KB (contiguous fp8 dst)
    uint8_t* xq = (uint8_t*)d_ws;
    uint8_t* yq = xq + (size_t)B_DIM * F_DIM;
    uint8_t* wq = yq + (size_t)B_DIM * F_DIM;
    float* rowsum = (float*)(wq + (size_t)N_DIM * F_DIM);

    const int n16_x = B_DIM * F_DIM / 16;
    const int n16_w = N_DIM * F_DIM / 16;
    const int total_thr = 2 * n16_x + n16_w + B_DIM / 4;  // cvt + rowsum-zero tail
    cvt_all_kernel<<<(total_thr + 255) / 256, 256, 0, stream>>>(
        x, y, wt, xq, rowsum, n16_x, n16_w);

    // Stage 1: scores = x . y^T, fused exp-rowsum
    gemm_bt_kernel<1><<<dim3(B_DIM / BN, B_DIM / BM), 256, 0, stream>>>(
        xq, yq, B_DIM, B_DIM, F_DIM, rowsum, nullptr, nullptr);

    // Stage 2: out = y . w^T + bias + hardswish(log(rowsum)), clamped
    gemm_bt_kernel<2><<<dim3(N_DIM / BN, B_DIM / BM), 256, 0, stream>>>(
        yq, wq, B_DIM, N_DIM, F_DIM, rowsum, bias, out);
}

// Round 8
// 336.911 us; speedup vs baseline: 1.1534x; 1.1534x over previous
//
#include <hip/hip_runtime.h>
#include <cstdint>
#include <cstddef>

// Problem constants (fixed by the reference: B=8192, F=1024, N=4096)
#define B_DIM 8192
#define F_DIM 1024
#define N_DIM 4096

// GEMM tiling: 128x128 block tile, 4 waves (2x2), 64x64 per wave, BK=128 fp8.
// Ladder so far: R3/R5 structure = 127 us GEMM1 (1082 TF). Measured dead ends:
//   R4 256x128 tile -> reg cliff (2x slower). R6 force-128-regs -> scratch
//   spills (WRITE 16->61 MB). R7 LDS double-buffer -> 2 blocks/CU + vmcnt(0)
//   drain at barrier anyway (168 us). Keep the R5 single-buffer K-loop.
// R8: GEMM2 epilogue was store-bound (64 scattered dword stores/lane, 64B
// segments); transpose through LDS (reuse staging buffer) -> float4 stores.
#define BM 128
#define BN 128
#define BK 128

typedef float floatx4 __attribute__((ext_vector_type(4)));
typedef int intx4 __attribute__((ext_vector_type(4)));
typedef int intx8 __attribute__((ext_vector_type(8)));

typedef const __attribute__((address_space(1))) unsigned int* as1_u32cp;
typedef __attribute__((address_space(3))) unsigned int* as3_u32p;

// Async global->LDS 16B copy. LDS dest is wave-uniform base + lane*16.
__device__ __forceinline__ void gload_lds16(const uint8_t* g, uint8_t* l) {
    __builtin_amdgcn_global_load_lds((as1_u32cp)(const unsigned int*)g,
                                     (as3_u32p)(unsigned int*)l, 16, 0, 0);
}

__device__ __forceinline__ float hardswish_f(float l) {
    float g = fminf(fmaxf(l + 3.0f, 0.0f), 6.0f);
    return l * g * (1.0f / 6.0f);
}

// Merged fp32 -> fp8 e4m3 conversion for x|y|w (dst contiguous in ws), plus a
// grid tail that zeroes rowsum (replaces a separate hipMemsetAsync dispatch).
__global__ __launch_bounds__(256) void cvt_all_kernel(
    const float* __restrict__ x, const float* __restrict__ y,
    const float* __restrict__ wt, uint8_t* __restrict__ dst,
    float* __restrict__ rowsum, int n16x, int n16w) {
    int i = blockIdx.x * 256 + threadIdx.x;
    int total = 2 * n16x + n16w;
    if (i >= total) {
        int r = i - total;
        if (r < B_DIM / 4) ((float4*)rowsum)[r] = make_float4(0.f, 0.f, 0.f, 0.f);
        return;
    }
    const float* src;
    int j;
    if (i < n16x) { src = x; j = i; }
    else if (i < 2 * n16x) { src = y; j = i - n16x; }
    else { src = wt; j = i - 2 * n16x; }
    const float4* s4 = (const float4*)src + 4 * (size_t)j;
    intx4 o;
#pragma unroll
    for (int q = 0; q < 4; ++q) {
        float4 v = s4[q];
        int p = __builtin_amdgcn_cvt_pk_fp8_f32(v.x, v.y, 0, false);
        p = __builtin_amdgcn_cvt_pk_fp8_f32(v.z, v.w, p, true);
        o[q] = p;
    }
    *(intx4*)(dst + 16 * (size_t)i) = o;
}

// C = A * B^T, A[M][K], Bm[N][K] row-major fp8 e4m3, fp32 accumulate via
// mfma_scale_f32_16x16x128_f8f6f4 with unit scales (E8M0 0x7F = 2^0).
// LDS XOR-swizzled in 16B chunks: slot (row,c) holds global chunk c^(row&7).
// A-fragment (16x16x128): row=lane&15, k = quad*32 + reg*4 + byte
// -> 32 contiguous bytes = swizzled chunks {(2q)^e, (2q+1)^e}, e=row&7.
// C/D layout: col=lane&15, row=quad*4+reg.
// MODE 1: epilogue sums exp(C[i][j]) into rowsum[i] (scores never hit HBM).
// MODE 2: epilogue out = clamp(C + bias + hardswish(log(rowsum[row])), -1, 1),
//         transposed through LDS (reusing the staging buffer, stride 132
//         floats: 16B-aligned rows, conflict-free ds_write) so global stores
//         are coalesced float4 (512B contiguous segments) instead of 64
//         scattered dword stores per lane.
template <int MODE>
__global__ __launch_bounds__(256, 3) void gemm_bt_kernel(
    const uint8_t* __restrict__ A,
    const uint8_t* __restrict__ Bm,
    int M, int N, int K,
    float* __restrict__ rowsum,
    const float* __restrict__ bias,
    float* __restrict__ out) {
    // 33.8 KB: staging (32 KB) during K-loop; 64x132 float pad-buffer after.
    __shared__ __align__(16) uint8_t smem[64 * 132 * 4];
    uint8_t* As = smem;            // 16 KB
    uint8_t* Bs = smem + 16384;    // 16 KB
    float* epi = (float*)smem;     // MODE 2 epilogue reuse

    const int t = threadIdx.x;
    const int w = t >> 6;
    const int lane = t & 63;
    const int quad = lane >> 4;
    const int lc = lane & 15;
    const int wm = w >> 1;   // wave row (0..1), 64 rows each
    const int wn = w & 1;    // wave col (0..1), 64 cols each
    const int rowBase = blockIdx.y * BM;
    const int colBase = blockIdx.x * BN;

    floatx4 acc[4][4];
#pragma unroll
    for (int mi = 0; mi < 4; ++mi)
#pragma unroll
        for (int ni = 0; ni < 4; ++ni)
            acc[mi][ni] = (floatx4){0.f, 0.f, 0.f, 0.f};

    const int nIter = K / BK;
    for (int kt = 0; kt < nIter; ++kt) {
        __syncthreads();  // prior iteration's LDS reads complete
#pragma unroll
        for (int c = 0; c < 4; ++c) {
            const int idx = c * 256 + t;       // 0..1023 -> 1024 16B chunks each
            const int row = idx >> 3;          // 0..127
            const int cg = (idx & 7) ^ (row & 7);
            gload_lds16(A + (size_t)(rowBase + row) * K + kt * BK + cg * 16, As + idx * 16);
            gload_lds16(Bm + (size_t)(colBase + row) * K + kt * BK + cg * 16, Bs + idx * 16);
        }
        __syncthreads();  // drains vmcnt: staged data visible

        intx8 af[4], bf[4];
#pragma unroll
        for (int mi = 0; mi < 4; ++mi) {
            const int row = wm * 64 + mi * 16 + lc;
            const int e = row & 7;
            ((intx4*)&af[mi])[0] = *(const intx4*)(As + row * BK + ((2 * quad) ^ e) * 16);
            ((intx4*)&af[mi])[1] = *(const intx4*)(As + row * BK + ((2 * quad + 1) ^ e) * 16);
        }
#pragma unroll
        for (int ni = 0; ni < 4; ++ni) {
            const int row = wn * 64 + ni * 16 + lc;
            const int e = row & 7;
            ((intx4*)&bf[ni])[0] = *(const intx4*)(Bs + row * BK + ((2 * quad) ^ e) * 16);
            ((intx4*)&bf[ni])[1] = *(const intx4*)(Bs + row * BK + ((2 * quad + 1) ^ e) * 16);
        }
#pragma unroll
        for (int mi = 0; mi < 4; ++mi)
#pragma unroll
            for (int ni = 0; ni < 4; ++ni)
                acc[mi][ni] = __builtin_amdgcn_mfma_scale_f32_16x16x128_f8f6f4(
                    af[mi], bf[ni], acc[mi][ni],
                    0, 0,                      // cbsz=fp8(e4m3), blgp=fp8(e4m3)
                    0, 0x7F7F7F7F,             // A scale: 1.0
                    0, 0x7F7F7F7F);            // B scale: 1.0
    }

    if constexpr (MODE == 1) {
        // sum exp over this wave's 64 columns for each of its 64 rows
#pragma unroll
        for (int mi = 0; mi < 4; ++mi) {
#pragma unroll
            for (int r = 0; r < 4; ++r) {
                float p = 0.f;
#pragma unroll
                for (int ni = 0; ni < 4; ++ni) p += __expf(acc[mi][ni][r]);
                // butterfly over the 16 columns held by this quad's 16 lanes
                p += __shfl_xor(p, 1, 16);
                p += __shfl_xor(p, 2, 16);
                p += __shfl_xor(p, 4, 16);
                p += __shfl_xor(p, 8, 16);
                if (lc == 0) {
                    int row = rowBase + wm * 64 + mi * 16 + quad * 4 + r;
                    atomicAdd(&rowsum[row], p);
                }
            }
        }
    } else {
        // Two halves (64 rows each): wave-row h dumps its (bias+addv+clamp)ed
        // tile into epi[64][132], then all 256 threads store coalesced float4.
#pragma unroll
        for (int h = 0; h < 2; ++h) {
            __syncthreads();  // epi free (staging reads / prior half done)
            if (wm == h) {
#pragma unroll
                for (int mi = 0; mi < 4; ++mi) {
                    const int lr0 = mi * 16 + quad * 4;    // local row 0..60
                    float av[4];
#pragma unroll
                    for (int r = 0; r < 4; ++r)
                        av[r] = hardswish_f(logf(rowsum[rowBase + h * 64 + lr0 + r]));
#pragma unroll
                    for (int ni = 0; ni < 4; ++ni) {
                        const int c = wn * 64 + ni * 16 + lc;
                        const float bv = bias[colBase + c];
#pragma unroll
                        for (int r = 0; r < 4; ++r) {
                            float v = acc[mi][ni][r] + bv + av[r];
                            v = fminf(fmaxf(v, -1.0f), 1.0f);
                            epi[(lr0 + r) * 132 + c] = v;
                        }
                    }
                }
            }
            __syncthreads();  // epi visible to all
#pragma unroll
            for (int k = 0; k < 8; ++k) {
                const int idx = k * 256 + t;     // 0..2047
                const int row = idx >> 5;        // 0..63
                const int c4 = (idx & 31) * 4;   // 0..124
                float4 v = *(const float4*)&epi[row * 132 + c4];
                *(float4*)&out[(size_t)(rowBase + h * 64 + row) * N + colBase + c4] = v;
            }
        }
    }
}

extern "C" void kernel_launch(void* const* d_in, const int* in_sizes, int n_in,
                              void* d_out, int out_size, void* d_ws, size_t ws_size,
                              hipStream_t stream) {
    const float* x = (const float*)d_in[0];     // [B, F]
    const float* y = (const float*)d_in[1];     // [B, F]
    const float* wt = (const float*)d_in[2];    // [N, F]
    const float* bias = (const float*)d_in[3];  // [N]
    float* out = (float*)d_out;                 // [B, N]

    // Workspace: xq 8MB | yq 8MB | wq 4MB | rowsum 32KB (contiguous fp8 dst)
    uint8_t* xq = (uint8_t*)d_ws;
    uint8_t* yq = xq + (size_t)B_DIM * F_DIM;
    uint8_t* wq = yq + (size_t)B_DIM * F_DIM;
    float* rowsum = (float*)(wq + (size_t)N_DIM * F_DIM);

    const int n16_x = B_DIM * F_DIM / 16;
    const int n16_w = N_DIM * F_DIM / 16;
    const int total_thr = 2 * n16_x + n16_w + B_DIM / 4;  // cvt + rowsum-zero tail
    cvt_all_kernel<<<(total_thr + 255) / 256, 256, 0, stream>>>(
        x, y, wt, xq, rowsum, n16_x, n16_w);

    // Stage 1: scores = x . y^T, fused exp-rowsum
    gemm_bt_kernel<1><<<dim3(B_DIM / BN, B_DIM / BM), 256, 0, stream>>>(
        xq, yq, B_DIM, B_DIM, F_DIM, rowsum, nullptr, nullptr);

    // Stage 2: out = y . w^T + bias + hardswish(log(rowsum)), clamped
    gemm_bt_kernel<2><<<dim3(N_DIM / BN, B_DIM / BM), 256, 0, stream>>>(
        yq, wq, B_DIM, N_DIM, F_DIM, rowsum, bias, out);
}